// Round 1
// baseline (32428.644 us; speedup 1.0000x reference)
//
#include <hip/hip_runtime.h>
#include <hip/hip_bf16.h>

typedef __attribute__((ext_vector_type(8))) short short8;
typedef __attribute__((ext_vector_type(4))) float f32x4;

#define MFMA_BF16(A, B, C) __builtin_amdgcn_mfma_f32_16x16x32_bf16((A), (B), (C), 0, 0, 0)

static constexpr int kB = 256;   // batch
static constexpr int kS = 512;   // seq
static constexpr int kI = 256;   // in_dim
static constexpr int kH = 2048;  // hidden
static constexpr int kC = 1024;  // classes

// LDS (dynamic, 147456 B):
//   [0,      131072): Whh slice, 32 n x 2048 k bf16, row stride 4096 B, XOR swizzled
//   [131072, 147456): Whx slice, 32 n x 256 k bf16, row stride 512 B, XOR swizzled
// After the recurrence the first region is reused for the Wph slice (16 n x 2048 k).

__device__ __forceinline__ int swz(int n, int kbyte, int rowstride) {
  return n * rowstride + (kbyte ^ ((n & 7) << 4));
}

__device__ __forceinline__ unsigned short f2bf(float f) {  // RNE fp32->bf16
  unsigned u = __float_as_uint(f);
  u += 0x7fffu + ((u >> 16) & 1u);
  return (unsigned short)(u >> 16);
}

__device__ __forceinline__ float fast_tanh(float v) {
  float a = __builtin_fabsf(v);
  float e = __expf(-2.0f * a);          // in (0,1], no overflow
  float r = (1.0f - e) / (1.0f + e);
  return __builtin_copysignf(r, v);
}

__global__ __launch_bounds__(256, 1)
void rnn_fused(const float* __restrict__ x, const float* __restrict__ Whx,
               const float* __restrict__ Whh, const float* __restrict__ Wph,
               const float* __restrict__ Bh, const float* __restrict__ Bp,
               float* __restrict__ out,
               unsigned short* __restrict__ h0buf,
               unsigned short* __restrict__ h1buf,
               unsigned* __restrict__ flags) {
  extern __shared__ char smem[];
  const int tid  = (int)threadIdx.x;
  const int lane = tid & 63;
  const int wv   = tid >> 6;
  const int wg   = (int)blockIdx.x;
  const int rg   = wg >> 6;   // 0..3  : 64-batch-row group (barrier domain)
  const int cg   = wg & 63;   // 0..63 : 32-hidden-col group
  const int r0   = rg * 64;
  const int n0   = cg * 32;

  // ---- stage weight slices into LDS (fp32 -> bf16, swizzled), once
  {
    const int c  = tid & 31;
    const int kk = tid >> 5;  // 8 k-stripes
    for (int k = kk; k < kH; k += 8)
      *(unsigned short*)(smem + swz(c, k * 2, 4096)) = f2bf(Whh[(size_t)k * kH + n0 + c]);
    for (int k = kk; k < kI; k += 8)
      *(unsigned short*)(smem + 131072 + swz(c, k * 2, 512)) = f2bf(Whx[(size_t)k * kH + n0 + c]);
  }
  __syncthreads();

  // MFMA 16x16x32 fragment geometry
  const int arow  = lane & 15;          // A row / B col / D col within tile
  const int klane = (lane >> 4) * 8;    // k offset within a 32-wide k-step
  const int rsub  = (wv & 1) * 32;      // wave's 32-row block within WG tile
  const int ctile = wv >> 1;            // wave's 16-col block (0/1)
  const int nloc  = ctile * 16 + arow;  // col within WG tile (0..31)
  const int ncol  = n0 + nloc;          // global hidden col
  const int gr0   = r0 + rsub + arow;   // global batch row, sub-tile 0
  const int gr1   = gr0 + 16;           // sub-tile 1

  const float bh = Bh[ncol];
  const float* px0 = x + (size_t)gr0 * (kS * kI);
  const float* px1 = x + (size_t)gr1 * (kS * kI);
  unsigned* gflags = flags + (rg << 6);

  for (int t = 0; t < kS; ++t) {
    const unsigned short* hc = (t & 1) ? h1buf : h0buf;
    unsigned short*       hn = (t & 1) ? h0buf : h1buf;
    f32x4 acc0 = {0.f, 0.f, 0.f, 0.f};
    f32x4 acc1 = {0.f, 0.f, 0.f, 0.f};

    // ---- x_t @ Whx  (K = 256), x is fp32, convert in-reg
    {
      const float* p0 = px0 + (size_t)t * kI + klane;
      const float* p1 = px1 + (size_t)t * kI + klane;
#pragma unroll
      for (int kb = 0; kb < kI / 32; ++kb) {
        f32x4 u0a = *(const f32x4*)(p0 + kb * 32);
        f32x4 u0b = *(const f32x4*)(p0 + kb * 32 + 4);
        f32x4 u1a = *(const f32x4*)(p1 + kb * 32);
        f32x4 u1b = *(const f32x4*)(p1 + kb * 32 + 4);
        short8 bfr = *(const short8*)(smem + 131072 + swz(nloc, kb * 64 + klane * 2, 512));
        short8 a0, a1;
#pragma unroll
        for (int j = 0; j < 4; ++j) {
          a0[j]     = (short)f2bf(u0a[j]);
          a0[j + 4] = (short)f2bf(u0b[j]);
          a1[j]     = (short)f2bf(u1a[j]);
          a1[j + 4] = (short)f2bf(u1b[j]);
        }
        acc0 = MFMA_BF16(a0, bfr, acc0);
        acc1 = MFMA_BF16(a1, bfr, acc1);
      }
    }

    // ---- h_t @ Whh  (K = 2048), h bf16 from global, Whh from LDS
    {
      const unsigned short* ph0 = hc + (size_t)gr0 * kH + klane;
      const unsigned short* ph1 = hc + (size_t)gr1 * kH + klane;
#pragma unroll 4
      for (int kb = 0; kb < kH / 32; ++kb) {
        short8 a0  = *(const short8*)(ph0 + kb * 32);
        short8 a1  = *(const short8*)(ph1 + kb * 32);
        short8 bfr = *(const short8*)(smem + swz(nloc, kb * 64 + klane * 2, 4096));
        acc0 = MFMA_BF16(a0, bfr, acc0);
        acc1 = MFMA_BF16(a1, bfr, acc1);
      }
    }

    // ---- epilogue: tanh -> h_next (bf16). D layout: row=(lane>>4)*4+j, col=lane&15
    {
      const int rb = r0 + rsub + (lane >> 4) * 4;
#pragma unroll
      for (int j = 0; j < 4; ++j) {
        hn[(size_t)(rb + j) * kH + ncol]      = f2bf(fast_tanh(acc0[j] + bh));
        hn[(size_t)(rb + 16 + j) * kH + ncol] = f2bf(fast_tanh(acc1[j] + bh));
      }
    }

    // ---- barrier among the 64 WGs sharing this 64-row batch group
    __threadfence();       // release h_next stores to device scope
    __syncthreads();
    if (tid == 0)
      __hip_atomic_store(&gflags[cg], (unsigned)(t + 1),
                         __ATOMIC_RELEASE, __HIP_MEMORY_SCOPE_AGENT);
    if (tid < 64) {        // wave 0: one lane spins per member WG flag
      while (__hip_atomic_load(&gflags[tid], __ATOMIC_ACQUIRE,
                               __HIP_MEMORY_SCOPE_AGENT) < (unsigned)(t + 1))
        __builtin_amdgcn_s_sleep(1);
    }
    __syncthreads();
    __builtin_amdgcn_fence(__ATOMIC_ACQUIRE, "agent");  // invalidate for fresh h reads
  }

  // ---- final projection: out = h_final @ Wph + Bp  (h_final = h0buf after 512 steps)
  {
    const int c  = tid & 15;
    const int kk = tid >> 4;  // 16 k-stripes
    for (int k = kk; k < kH; k += 16)
      *(unsigned short*)(smem + swz(c, k * 2, 4096)) = f2bf(Wph[(size_t)k * kC + cg * 16 + c]);
  }
  __syncthreads();
  {
    const int frow = r0 + wv * 16 + arow;  // A row
    const int fcol = cg * 16 + arow;       // B/D col
    f32x4 acc = {0.f, 0.f, 0.f, 0.f};
    const unsigned short* ph = h0buf + (size_t)frow * kH + klane;
#pragma unroll 4
    for (int kb = 0; kb < kH / 32; ++kb) {
      short8 a = *(const short8*)(ph + kb * 32);
      short8 b = *(const short8*)(smem + swz(arow, kb * 64 + klane * 2, 4096));
      acc = MFMA_BF16(a, b, acc);
    }
    const float bp = Bp[fcol];
    const int orow = r0 + wv * 16 + (lane >> 4) * 4;
#pragma unroll
    for (int j = 0; j < 4; ++j)
      out[(size_t)(orow + j) * kC + fcol] = acc[j] + bp;
  }
}

extern "C" void kernel_launch(void* const* d_in, const int* in_sizes, int n_in,
                              void* d_out, int out_size, void* d_ws, size_t ws_size,
                              hipStream_t stream) {
  const float* x   = (const float*)d_in[0];
  const float* Whx = (const float*)d_in[1];
  const float* Whh = (const float*)d_in[2];
  const float* Wph = (const float*)d_in[3];
  const float* Bh  = (const float*)d_in[4];
  const float* Bp  = (const float*)d_in[5];
  float* out = (float*)d_out;

  char* ws = (char*)d_ws;
  unsigned short* h0 = (unsigned short*)(ws);                 // 1 MB: h ping
  unsigned short* h1 = (unsigned short*)(ws + (1 << 20));     // 1 MB: h pong
  unsigned* flags    = (unsigned*)(ws + (2 << 20));           // 4*64 step flags

  hipMemsetAsync(h0, 0, (size_t)kB * kH * sizeof(unsigned short), stream);  // h_0 = 0
  hipMemsetAsync(flags, 0, 4096, stream);                                   // reset barrier

  dim3 grid(256), block(256);
  size_t lds = 147456;  // 128 KB Whh + 16 KB Whx
  hipLaunchKernelGGL(rnn_fused, grid, block, lds, stream,
                     x, Whx, Whh, Wph, Bh, Bp, out, h0, h1, flags);
}

// Round 2
// 8833.353 us; speedup vs baseline: 3.6712x; 3.6712x over previous
//
#include <hip/hip_runtime.h>
#include <hip/hip_bf16.h>

typedef __attribute__((ext_vector_type(8))) short short8;
typedef __attribute__((ext_vector_type(4))) float f32x4;
typedef unsigned long long u64;

#define MFMA_BF16(A, B, C) __builtin_amdgcn_mfma_f32_16x16x32_bf16((A), (B), (C), 0, 0, 0)

static constexpr int kS = 512;   // seq
static constexpr int kI = 256;   // in_dim
static constexpr int kH = 2048;  // hidden
static constexpr int kC = 1024;  // classes
static constexpr int kBt = 256;  // batch

// LDS (dynamic, 147456 B):
//   [0,      131072): Whh^T slice: [n=32][k=2048] bf16, row stride 4096 B, XOR swizzled
//   [131072, 147456): Whx^T slice: [n=32][k=256]  bf16, row stride 512 B,  XOR swizzled
// After the recurrence, region 0 is reused for Wph^T [c=16][k=2048].

__device__ __forceinline__ int swz(int n, int kbyte, int rowstride) {
  return n * rowstride + (kbyte ^ ((n & 7) << 4));
}

__device__ __forceinline__ unsigned short f2bf(float f) {  // RNE fp32->bf16
  unsigned u = __float_as_uint(f);
  u += 0x7fffu + ((u >> 16) & 1u);
  return (unsigned short)(u >> 16);
}

__device__ __forceinline__ float fast_tanh(float v) {
  float a = __builtin_fabsf(v);
  float e = __expf(-2.0f * a);
  float r = (1.0f - e) / (1.0f + e);
  return __builtin_copysignf(r, v);
}

// Agent-scope relaxed atomics: lower to global_load/store with sc0 sc1
// (bypass L1/L2, coherent at LLC) -- NO buffer_wbl2 / buffer_inv emitted.
__device__ __forceinline__ u64 ld_h8(const u64* p) {
  return __hip_atomic_load(p, __ATOMIC_RELAXED, __HIP_MEMORY_SCOPE_AGENT);
}
__device__ __forceinline__ void st_h8(u64* p, u64 v) {
  __hip_atomic_store(p, v, __ATOMIC_RELAXED, __HIP_MEMORY_SCOPE_AGENT);
}
__device__ __forceinline__ unsigned ld_flag(const unsigned* p) {
  return __hip_atomic_load(p, __ATOMIC_RELAXED, __HIP_MEMORY_SCOPE_AGENT);
}
__device__ __forceinline__ void st_flag(unsigned* p, unsigned v) {
  __hip_atomic_store(p, v, __ATOMIC_RELAXED, __HIP_MEMORY_SCOPE_AGENT);
}

__global__ __launch_bounds__(256, 1)
void rnn_fused(const float* __restrict__ x, const float* __restrict__ Whx,
               const float* __restrict__ Whh, const float* __restrict__ Wph,
               const float* __restrict__ Bh, const float* __restrict__ Bp,
               float* __restrict__ out,
               u64* __restrict__ h0buf, u64* __restrict__ h1buf,
               unsigned* __restrict__ flags) {
  extern __shared__ char smem[];
  const int tid = (int)threadIdx.x;
  const int lane = tid & 63;
  const int wv = tid >> 6;
  const int wg = (int)blockIdx.x;
  const int rg = wg >> 6;   // 0..3  : 64-batch-row group (barrier domain)
  const int cg = wg & 63;   // 0..63 : 32-hidden-col group
  const int r0 = rg * 64;
  const int n0 = cg * 32;

  // ---- stage weight slices into LDS (fp32 -> bf16, swizzled), once
  {
    const int c = tid & 31;
    const int kk = tid >> 5;  // 8 k-stripes
    for (int k = kk; k < kH; k += 8)
      *(unsigned short*)(smem + swz(c, k * 2, 4096)) = f2bf(Whh[(size_t)k * kH + n0 + c]);
    for (int k = kk; k < kI; k += 8)
      *(unsigned short*)(smem + 131072 + swz(c, k * 2, 512)) = f2bf(Whx[(size_t)k * kH + n0 + c]);
  }
  __syncthreads();

  // Fragment geometry (swapped operands: D = W^T x h^T, so D cols = h rows)
  const int bcol = lane & 15;              // B-col: h/x row within wave tile; also A-row
  const int kseg = lane >> 4;              // k segment (0..3)
  const int row  = r0 + wv * 16 + bcol;    // this lane's batch row (waves stack 16 rows)
  const int dcol0 = n0 + kseg * 4;         // 4 consecutive hidden cols, tile 0
  const int dcol1 = dcol0 + 16;            // tile 1

  const f32x4 bh0 = *(const f32x4*)(Bh + dcol0);
  const f32x4 bh1 = *(const f32x4*)(Bh + dcol1);

  unsigned* gflags = flags + (rg << 6);
  const float* px_row = x + (size_t)row * (kS * kI) + kseg * 8;

  for (int t = 0; t < kS; ++t) {
    const u64* hc = (t & 1) ? h1buf : h0buf;
    u64* hn       = (t & 1) ? h0buf : h1buf;
    f32x4 acc0 = {0.f, 0.f, 0.f, 0.f};
    f32x4 acc1 = {0.f, 0.f, 0.f, 0.f};

    // ---- x_t @ Whx (K=256): overlaps the barrier wait below (no h dependence)
    {
      const float* px = px_row + (size_t)t * kI;
#pragma unroll
      for (int kb = 0; kb < kI / 32; ++kb) {
        f32x4 xa = *(const f32x4*)(px + kb * 32);
        f32x4 xb = *(const f32x4*)(px + kb * 32 + 4);
        short8 bf;
#pragma unroll
        for (int j = 0; j < 4; ++j) {
          bf[j]     = (short)f2bf(xa[j]);
          bf[j + 4] = (short)f2bf(xb[j]);
        }
        short8 a0 = *(const short8*)(smem + 131072 + swz(bcol,      (kb * 32 + kseg * 8) * 2, 512));
        short8 a1 = *(const short8*)(smem + 131072 + swz(16 + bcol, (kb * 32 + kseg * 8) * 2, 512));
        acc0 = MFMA_BF16(a0, bf, acc0);
        acc1 = MFMA_BF16(a1, bf, acc1);
      }
    }

    // ---- wait for h_t (each wave spins independently; 64 lanes poll 64 flags)
    if (t > 0) {
      while (!__all((int)(ld_flag(&gflags[lane]) >= (unsigned)t)))
        __builtin_amdgcn_s_sleep(1);
      asm volatile("" ::: "memory");
    }

    // ---- h_t @ Whh (K=2048): h via sc1 LLC loads, Whh^T from LDS
    {
      const u64* ph = hc + (size_t)row * (kH / 4) + kseg * 2;
#pragma unroll 8
      for (int kb = 0; kb < kH / 32; ++kb) {
        union { u64 q[2]; short8 s; } u;
        u.q[0] = ld_h8(ph + kb * 8);
        u.q[1] = ld_h8(ph + kb * 8 + 1);
        short8 a0 = *(const short8*)(smem + swz(bcol,      (kb * 32 + kseg * 8) * 2, 4096));
        short8 a1 = *(const short8*)(smem + swz(16 + bcol, (kb * 32 + kseg * 8) * 2, 4096));
        acc0 = MFMA_BF16(a0, u.s, acc0);
        acc1 = MFMA_BF16(a1, u.s, acc1);
      }
    }

    // ---- epilogue: tanh -> pack 4 bf16 -> one 8B agent store per tile
    {
      u64 v0 = 0, v1 = 0;
#pragma unroll
      for (int j = 0; j < 4; ++j) {
        v0 |= (u64)f2bf(fast_tanh(acc0[j] + bh0[j])) << (16 * j);
        v1 |= (u64)f2bf(fast_tanh(acc1[j] + bh1[j])) << (16 * j);
      }
      u64* pr = hn + (size_t)row * (kH / 4);
      st_h8(pr + (dcol0 >> 2), v0);
      st_h8(pr + (dcol1 >> 2), v1);
    }

    // ---- release: __syncthreads drains vmcnt(0) (sc1 stores ack'd at LLC)
    __syncthreads();
    if (tid == 0) st_flag(&gflags[cg], (unsigned)(t + 1));
  }

  // ---- wait for the whole rowgroup to finish step 512, then final projection
  while (!__all((int)(ld_flag(&gflags[lane]) >= (unsigned)kS)))
    __builtin_amdgcn_s_sleep(1);
  asm volatile("" ::: "memory");
  __syncthreads();

  // stage Wph^T slice [c=16][k=2048] into LDS region 0
  {
    const int c = tid & 15;
    const int kk = tid >> 4;  // 16 k-stripes
    for (int k = kk; k < kH; k += 16)
      *(unsigned short*)(smem + swz(c, k * 2, 4096)) = f2bf(Wph[(size_t)k * kC + cg * 16 + c]);
  }
  __syncthreads();

  // out = h_final @ Wph + Bp ; h_final lives in h0buf (step 511 wrote it)
  {
    f32x4 acc = {0.f, 0.f, 0.f, 0.f};
    const u64* ph = h0buf + (size_t)row * (kH / 4) + kseg * 2;
#pragma unroll 8
    for (int kb = 0; kb < kH / 32; ++kb) {
      union { u64 q[2]; short8 s; } u;
      u.q[0] = ld_h8(ph + kb * 8);
      u.q[1] = ld_h8(ph + kb * 8 + 1);
      short8 b = *(const short8*)(smem + swz(bcol, (kb * 32 + kseg * 8) * 2, 4096));
      acc = MFMA_BF16(u.s, b, acc);  // A = h rows, B = Wph cols
    }
    const float bp = Bp[cg * 16 + bcol];
    const int orow = r0 + wv * 16 + kseg * 4;
#pragma unroll
    for (int j = 0; j < 4; ++j)
      out[(size_t)(orow + j) * kC + cg * 16 + bcol] = acc[j] + bp;
  }
}

extern "C" void kernel_launch(void* const* d_in, const int* in_sizes, int n_in,
                              void* d_out, int out_size, void* d_ws, size_t ws_size,
                              hipStream_t stream) {
  const float* x   = (const float*)d_in[0];
  const float* Whx = (const float*)d_in[1];
  const float* Whh = (const float*)d_in[2];
  const float* Wph = (const float*)d_in[3];
  const float* Bh  = (const float*)d_in[4];
  const float* Bp  = (const float*)d_in[5];
  float* out = (float*)d_out;

  char* ws = (char*)d_ws;
  u64* h0         = (u64*)(ws);                 // 1 MB: h ping
  u64* h1         = (u64*)(ws + (1 << 20));     // 1 MB: h pong
  unsigned* flags = (unsigned*)(ws + (2 << 20)); // 4 groups x 64 step flags

  hipMemsetAsync(h0, 0, (size_t)kBt * kH * sizeof(unsigned short), stream);  // h_0 = 0
  hipMemsetAsync(flags, 0, 4096, stream);                                    // reset barrier

  dim3 grid(256), block(256);
  size_t lds = 147456;  // 128 KB Whh + 16 KB Whx
  hipLaunchKernelGGL(rnn_fused, grid, block, lds, stream,
                     x, Whx, Whh, Wph, Bh, Bp, out, h0, h1, flags);
}